// Round 8
// baseline (188.389 us; speedup 1.0000x reference)
//
#include <hip/hip_runtime.h>
#include <hip/hip_bf16.h>
#include <math.h>

#define NPIX 2304
#define CCH  128
#define NH   4
#define HC   32
#define NCL  16
#define KSPLIT 8
#define KEYS 288
#define NSTEP 9
#define QSCALE 0.25503489f               // log2(e)/sqrt(32)
#define PPT  16

typedef __attribute__((ext_vector_type(8))) short short8;
typedef __attribute__((ext_vector_type(4))) float f32x4;

#if __has_builtin(__builtin_amdgcn_exp2f)
#define EXP2(x) __builtin_amdgcn_exp2f(x)
#else
#define EXP2(x) __expf((x) * 0.6931471805599453f)
#endif

static __device__ __forceinline__ short f2bf(float x) {
    __hip_bfloat16 b = __float2bfloat16(x);
    return *reinterpret_cast<short*>(&b);
}

// ---------------- Kernel 1: q/k/v projections + centersA partials (r7 body) ----
__global__ void __launch_bounds__(256) proj_kernel(
        const float* __restrict__ xq, const float* __restrict__ xk,
        const float* __restrict__ xv, const int* __restrict__ labels,
        const float* __restrict__ wq, const float* __restrict__ bq,
        const float* __restrict__ wk, const float* __restrict__ bk,
        const float* __restrict__ wv, const float* __restrict__ bv,
        short* __restrict__ qbf, short* __restrict__ kbf,
        float* __restrict__ vbuf, short* __restrict__ vbfT,
        float* __restrict__ cpart, float* __restrict__ denpart) {
    __shared__ float xsP[CCH * PPT];          // 8 KB
    __shared__ float ls2[2 * NCL * CCH];      // 16 KB
    __shared__ float smls[32];
    const int which = blockIdx.y;
    const int pxblk = blockIdx.x;
    const int n0    = pxblk * PPT;
    const int t  = threadIdx.x;
    const int c  = t & 127;
    const int ph = t >> 7;
    const float* x = (which == 0) ? xq : (which == 1) ? xk : xv;
    const float* w = (which == 0) ? wq : (which == 1) ? wk : wv;
    const float* b = (which == 0) ? bq : (which == 1) ? bk : bv;

#pragma unroll
    for (int it = 0; it < 8; ++it) {
        const int flat = it * 256 + t;
        const int cc = flat >> 4;
        const int p  = flat & 15;
        xsP[flat] = x[cc * NPIX + n0 + p];
    }
    if (which == 1)
        for (int u = t; u < 2 * NCL * CCH; u += 256) ls2[u] = 0.f;
    __syncthreads();

    float acc[8];
    const float bb = b[c];
#pragma unroll
    for (int p = 0; p < 8; ++p) acc[p] = bb;

#pragma unroll 4
    for (int in = 0; in < CCH; ++in) {
        const float wv_ = w[in * CCH + c];
        const float4 xa = *(const float4*)(xsP + in * PPT + ph * 8);
        const float4 xb = *(const float4*)(xsP + in * PPT + ph * 8 + 4);
        acc[0] = fmaf(xa.x, wv_, acc[0]); acc[1] = fmaf(xa.y, wv_, acc[1]);
        acc[2] = fmaf(xa.z, wv_, acc[2]); acc[3] = fmaf(xa.w, wv_, acc[3]);
        acc[4] = fmaf(xb.x, wv_, acc[4]); acc[5] = fmaf(xb.y, wv_, acc[5]);
        acc[6] = fmaf(xb.z, wv_, acc[6]); acc[7] = fmaf(xb.w, wv_, acc[7]);
    }

    const int nb = n0 + ph * 8;
    if (which == 0) {
#pragma unroll
        for (int p = 0; p < 8; ++p)
            qbf[(size_t)(nb + p) * CCH + c] = f2bf(acc[p] * QSCALE);
    } else if (which == 1) {
#pragma unroll
        for (int p = 0; p < 8; ++p)
            kbf[(size_t)(nb + p) * CCH + c] = f2bf(acc[p]);
        // center partials: thread owns column (ph,c) of ls2 -> race-free
        int lab8[8];
#pragma unroll
        for (int p = 0; p < 8; ++p) lab8[p] = labels[nb + p];
#pragma unroll
        for (int p = 0; p < 8; ++p)
            ls2[(ph * NCL + lab8[p]) * CCH + c] += acc[p];
        if (t < 32) {
            const int g2 = t >> 4, cl = t & 15;
            int cnt = 0;
#pragma unroll
            for (int p = 0; p < 8; ++p)
                cnt += (labels[n0 + g2 * 8 + p] == cl) ? 1 : 0;
            smls[t] = (float)cnt;
        }
        __syncthreads();
        for (int u = t; u < NCL * CCH; u += 256)
            cpart[(size_t)pxblk * 2048 + u] = ls2[u] + ls2[2048 + u];
        if (t < 16)
            denpart[pxblk * 16 + t] = smls[t] + smls[16 + t];
    } else {
#pragma unroll
        for (int p = 0; p < 8; ++p) vbuf[(size_t)(nb + p) * CCH + c] = acc[p];
        short8 s0;
#pragma unroll
        for (int p = 0; p < 8; ++p) s0[p] = f2bf(acc[p]);
        *(short8*)(vbfT + (size_t)c * NPIX + nb) = s0;
    }
}

// ---------------- Kernel 2: reduce partials -> bf16 centers ----------------
__global__ void centersB_kernel(const float* __restrict__ cpart,
                                const float* __restrict__ denpart,
                                short* __restrict__ cbf) {
    const int idx = blockIdx.x * 256 + threadIdx.x;   // 0..2047
    const int kk  = idx >> 7;
    float den = 0.f, s = 0.f;
    for (int b = 0; b < 144; ++b) den += denpart[b * 16 + kk];
    for (int b = 0; b < 144; ++b) s   += cpart[(size_t)b * 2048 + idx];
    cbf[idx] = f2bf(s / (den + 1e-6f));
}

// ---------------- Kernel 3: MFMA attention (r7-verified barrier-free body) -----
__global__ void __launch_bounds__(256, 4) attn_part_kernel(
        const short* __restrict__ qbf,  const short* __restrict__ kbf,
        const short* __restrict__ vbfT, const short* __restrict__ cbf,
        const int* __restrict__ labels, const float* __restrict__ pc,
        float* __restrict__ part_o, float* __restrict__ part_l) {
    __shared__ __align__(16) short Pl[NH][16 * 40];
    __shared__ __align__(16) float aclT[NH][16][16];
    __shared__ int   labl[KEYS];
    const int qt   = blockIdx.x;
    const int ks   = blockIdx.y;
    const int tid  = threadIdx.x;
    const int w    = tid >> 6;
    const int lane = tid & 63;
    const int quad = lane >> 4;
    const int lq   = lane & 15;
    const int i0   = qt * 16;
    const int j0   = ks * KEYS;

    for (int u = tid; u < KEYS / 4; u += 256)
        *(int4*)(labl + u * 4) = *(const int4*)(labels + j0 + u * 4);

    const short8 aq = *(const short8*)(qbf + (size_t)(i0 + lq) * CCH + w * HC + quad * 8);
    {
        const short8 bc = *(const short8*)(cbf + (size_t)lq * CCH + w * HC + quad * 8);
        f32x4 z = {0.f, 0.f, 0.f, 0.f};
        f32x4 acd = __builtin_amdgcn_mfma_f32_16x16x32_bf16(aq, bc, z, 0, 0, 0);
        *(f32x4*)(&aclT[w][lq][quad * 4]) = acd;   // [center][q-row], wave-private
    }
    int labi[4];
#pragma unroll
    for (int r = 0; r < 4; ++r) labi[r] = labels[i0 + quad * 4 + r];

    __syncthreads();   // labl ready

    const short* kp  = kbf  + (size_t)(j0 + lq) * CCH + w * HC + quad * 8;
    const short* vp  = vbfT + (size_t)(w * HC + lq) * NPIX + j0 + quad * 8;
    const float* pcp = pc   + (size_t)(i0 + quad * 4) * NPIX + j0 + lq;

    short8 k0A, k1A, v0A, v1A, k0B, k1B, v0B, v1B;
    float pcA[8], pcB[8];
    f32x4 accO0 = {0.f, 0.f, 0.f, 0.f};
    f32x4 accO1 = {0.f, 0.f, 0.f, 0.f};
    float lp[4] = {0.f, 0.f, 0.f, 0.f};

#define ISSUE(K0_, K1_, V0_, V1_, s) do {                                         \
        K0_ = *(const short8*)(kp + (size_t)(s) * 32 * CCH);                      \
        K1_ = *(const short8*)(kp + (size_t)((s) * 32 + 16) * CCH);               \
        V0_ = *(const short8*)(vp + (s) * 32);                                    \
        V1_ = *(const short8*)(vp + (size_t)16 * NPIX + (s) * 32);                \
    } while (0)

#define ISSUE_PC(dst, s) do {                                                     \
        _Pragma("unroll")                                                         \
        for (int r_ = 0; r_ < 4; ++r_) {                                          \
            dst[r_ * 2 + 0] = pcp[(size_t)r_ * NPIX + (s) * 32];                  \
            dst[r_ * 2 + 1] = pcp[(size_t)r_ * NPIX + (s) * 32 + 16];             \
        }                                                                         \
    } while (0)

#define COMPUTE(s, K0_, K1_, V0_, V1_, PCUSE) do {                                \
        _Pragma("unroll")                                                         \
        for (int kh = 0; kh < 2; ++kh) {                                          \
            const short8 bk = (kh == 0) ? K0_ : K1_;                              \
            f32x4 z = {0.f, 0.f, 0.f, 0.f};                                       \
            const f32x4 sv = __builtin_amdgcn_mfma_f32_16x16x32_bf16(aq, bk, z, 0, 0, 0);\
            const int slab = labl[(s) * 32 + kh * 16 + lq];                       \
            const f32x4 av4 = *(const f32x4*)(&aclT[w][slab][quad * 4]);          \
            _Pragma("unroll")                                                     \
            for (int r = 0; r < 4; ++r) {                                         \
                const float sc_ = (slab == labi[r]) ? sv[r] : av4[r] * PCUSE[r * 2 + kh];\
                const float p   = EXP2(sc_);                                      \
                lp[r] += p;                                                       \
                Pl[w][(quad * 4 + r) * 40 + kh * 16 + lq] = f2bf(p);              \
            }                                                                     \
        }                                                                         \
        const short8 ap = *(const short8*)(&Pl[w][lq * 40 + quad * 8]);           \
        accO0 = __builtin_amdgcn_mfma_f32_16x16x32_bf16(ap, V0_, accO0, 0, 0, 0); \
        accO1 = __builtin_amdgcn_mfma_f32_16x16x32_bf16(ap, V1_, accO1, 0, 0, 0); \
    } while (0)

    ISSUE(k0A, k1A, v0A, v1A, 0);
    ISSUE_PC(pcA, 0);
    for (int sb = 0; sb < NSTEP; sb += 2) {
        if (sb + 1 < NSTEP) { ISSUE(k0B, k1B, v0B, v1B, sb + 1); ISSUE_PC(pcB, sb + 1); }
        COMPUTE(sb, k0A, k1A, v0A, v1A, pcA);
        if (sb + 1 < NSTEP) {
            if (sb + 2 < NSTEP) { ISSUE(k0A, k1A, v0A, v1A, sb + 2); ISSUE_PC(pcA, sb + 2); }
            COMPUTE(sb + 1, k0B, k1B, v0B, v1B, pcB);
        }
    }
#undef ISSUE
#undef ISSUE_PC
#undef COMPUTE

#pragma unroll
    for (int r = 0; r < 4; ++r) {
        float v = lp[r];
        v += __shfl_xor(v, 1, 64);
        v += __shfl_xor(v, 2, 64);
        v += __shfl_xor(v, 4, 64);
        v += __shfl_xor(v, 8, 64);
        lp[r] = v;
    }
    if (lq == 0) {
#pragma unroll
        for (int r = 0; r < 4; ++r)
            part_l[((size_t)ks * NPIX + i0 + quad * 4 + r) * NH + w] = lp[r];
    }
#pragma unroll
    for (int r = 0; r < 4; ++r) {
        float* po = part_o + ((size_t)ks * NPIX + i0 + quad * 4 + r) * CCH + w * HC;
        po[lq]      = accO0[r];
        po[16 + lq] = accO1[r];
    }
}

// ---------------- Kernel 4: fused per-pixel MLP chain, 4 px/block --------------
// r7 body rescaled 8->4 px/block: 576 blocks (~2.25/CU, ~9 waves/CU) to hide
// L2/HBM latency through the serial stage chain. LDS 10 KB.
__global__ void __launch_bounds__(256) mlp_chain_kernel(
        const float* __restrict__ part_o, const float* __restrict__ part_l,
        const float* __restrict__ vbuf,
        const float* __restrict__ w1a, const float* __restrict__ b1a,
        const float* __restrict__ w1b, const float* __restrict__ b1b,
        const float* __restrict__ w2a, const float* __restrict__ b2a,
        const float* __restrict__ w2b, const float* __restrict__ b2b,
        float* __restrict__ outp) {
    __shared__ float xs[4 * CCH];             // 2 KB  attn out
    __shared__ float hL[4 * 2 * CCH];         // 4 KB  hidden (both MLPs)
    __shared__ float r1L[4 * CCH];            // 2 KB  rs1
    __shared__ float fT[CCH * 4];             // 2 KB  final transposed
    const int n0 = blockIdx.x * 4;
    const int t  = threadIdx.x;

    // stage: softmax-normalized attention output (reduce over ks splits)
    if (t < 128) {
        const int p = t >> 5, c4 = (t & 31) * 4;
        const int hh2 = c4 >> 5;
        float ls_ = 0.f;
#pragma unroll
        for (int ks = 0; ks < KSPLIT; ++ks)
            ls_ += part_l[((size_t)ks * NPIX + n0 + p) * NH + hh2];
        float sx = 0.f, sy = 0.f, sz = 0.f, sw2 = 0.f;
#pragma unroll
        for (int ks = 0; ks < KSPLIT; ++ks) {
            const float4 v = *(const float4*)(part_o + ((size_t)ks * NPIX + n0 + p) * CCH + c4);
            sx += v.x; sy += v.y; sz += v.z; sw2 += v.w;
        }
        const float inv = 1.f / ls_;
        xs[p * CCH + c4 + 0] = sx * inv;
        xs[p * CCH + c4 + 1] = sy * inv;
        xs[p * CCH + c4 + 2] = sz * inv;
        xs[p * CCH + c4 + 3] = sw2 * inv;
    }
    __syncthreads();

    const int c  = t & 127;
    const int pg = t >> 7;                    // 0..1 (wave-uniform): px pg*2..pg*2+1

    // ---- MLP1 hidden: thread owns hidden unit t for 4 px ----
    {
        float ha[4];
        const float b1 = b1a[t];
#pragma unroll
        for (int p = 0; p < 4; ++p) ha[p] = b1;
        for (int in = 0; in < CCH; in += 4) {
            const float w0 = w1a[(in + 0) * 2 * CCH + t];
            const float w1 = w1a[(in + 1) * 2 * CCH + t];
            const float w2 = w1a[(in + 2) * 2 * CCH + t];
            const float w3 = w1a[(in + 3) * 2 * CCH + t];
#pragma unroll
            for (int p = 0; p < 4; ++p) {
                const float4 xv = *(const float4*)(xs + p * CCH + in);
                ha[p] = fmaf(xv.x, w0, ha[p]); ha[p] = fmaf(xv.y, w1, ha[p]);
                ha[p] = fmaf(xv.z, w2, ha[p]); ha[p] = fmaf(xv.w, w3, ha[p]);
            }
        }
#pragma unroll
        for (int p = 0; p < 4; ++p) {
            const float v = ha[p];
            hL[p * 2 * CCH + t] = (v > 0.f) ? v : 0.01f * v;
        }
    }
    __syncthreads();

    // ---- MLP1 out + residual v -> rs1 (LDS); thread owns channel c for 2 px ----
    {
        float oa[2];
        const float bo = b1b[c];
        oa[0] = bo; oa[1] = bo;
        for (int k = 0; k < 2 * CCH; k += 4) {
            const float w0 = w1b[(k + 0) * CCH + c];
            const float w1 = w1b[(k + 1) * CCH + c];
            const float w2 = w1b[(k + 2) * CCH + c];
            const float w3 = w1b[(k + 3) * CCH + c];
#pragma unroll
            for (int j = 0; j < 2; ++j) {
                const float4 hv = *(const float4*)(hL + (pg * 2 + j) * 2 * CCH + k);
                oa[j] = fmaf(hv.x, w0, oa[j]); oa[j] = fmaf(hv.y, w1, oa[j]);
                oa[j] = fmaf(hv.z, w2, oa[j]); oa[j] = fmaf(hv.w, w3, oa[j]);
            }
        }
#pragma unroll
        for (int j = 0; j < 2; ++j)
            r1L[(pg * 2 + j) * CCH + c] =
                vbuf[(size_t)(n0 + pg * 2 + j) * CCH + c] + oa[j];
    }
    __syncthreads();

    // ---- MLP2 hidden (reads rs1, overwrites hL) ----
    {
        float ha[4];
        const float b2 = b2a[t];
#pragma unroll
        for (int p = 0; p < 4; ++p) ha[p] = b2;
        for (int in = 0; in < CCH; in += 4) {
            const float w0 = w2a[(in + 0) * 2 * CCH + t];
            const float w1 = w2a[(in + 1) * 2 * CCH + t];
            const float w2 = w2a[(in + 2) * 2 * CCH + t];
            const float w3 = w2a[(in + 3) * 2 * CCH + t];
#pragma unroll
            for (int p = 0; p < 4; ++p) {
                const float4 xv = *(const float4*)(r1L + p * CCH + in);
                ha[p] = fmaf(xv.x, w0, ha[p]); ha[p] = fmaf(xv.y, w1, ha[p]);
                ha[p] = fmaf(xv.z, w2, ha[p]); ha[p] = fmaf(xv.w, w3, ha[p]);
            }
        }
        __syncthreads();   // hL WAR
#pragma unroll
        for (int p = 0; p < 4; ++p) {
            const float v = ha[p];
            hL[p * 2 * CCH + t] = (v > 0.f) ? v : 0.01f * v;
        }
    }
    __syncthreads();

    // ---- MLP2 out + residual rs1 -> fT[c][px] ----
    {
        float oa[2];
        const float bo = b2b[c];
        oa[0] = bo; oa[1] = bo;
        for (int k = 0; k < 2 * CCH; k += 4) {
            const float w0 = w2b[(k + 0) * CCH + c];
            const float w1 = w2b[(k + 1) * CCH + c];
            const float w2 = w2b[(k + 2) * CCH + c];
            const float w3 = w2b[(k + 3) * CCH + c];
#pragma unroll
            for (int j = 0; j < 2; ++j) {
                const float4 hv = *(const float4*)(hL + (pg * 2 + j) * 2 * CCH + k);
                oa[j] = fmaf(hv.x, w0, oa[j]); oa[j] = fmaf(hv.y, w1, oa[j]);
                oa[j] = fmaf(hv.z, w2, oa[j]); oa[j] = fmaf(hv.w, w3, oa[j]);
            }
        }
#pragma unroll
        for (int j = 0; j < 2; ++j)
            fT[c * 4 + pg * 2 + j] = r1L[(pg * 2 + j) * CCH + c] + oa[j];
    }
    __syncthreads();

    // ---- coalesced final store: out[c][n0..n0+4) as one float4 per row ----
    if (t < 128) {
        const float4 v = *(const float4*)(fT + t * 4);
        *(float4*)(outp + (size_t)t * NPIX + n0) = v;
    }
}

extern "C" void kernel_launch(void* const* d_in, const int* in_sizes, int n_in,
                              void* d_out, int out_size, void* d_ws, size_t ws_size,
                              hipStream_t stream) {
    const float* q_img = (const float*)d_in[0];
    const float* k_img = (const float*)d_in[1];
    const float* v_img = (const float*)d_in[2];
    const float* pc    = (const float*)d_in[3];
    const int*   labels= (const int*)  d_in[4];
    const float* wq = (const float*)d_in[5];   const float* bq = (const float*)d_in[6];
    const float* wk = (const float*)d_in[7];   const float* bk = (const float*)d_in[8];
    const float* wv = (const float*)d_in[9];   const float* bv = (const float*)d_in[10];
    const float* w1a = (const float*)d_in[11]; const float* b1a = (const float*)d_in[12];
    const float* w1b = (const float*)d_in[13]; const float* b1b = (const float*)d_in[14];
    const float* w2a = (const float*)d_in[15]; const float* b2a = (const float*)d_in[16];
    const float* w2b = (const float*)d_in[17]; const float* b2b = (const float*)d_in[18];

    float* fw = (float*)d_ws;
    float* vbuf    = fw;                                   // [N][128]
    float* part_o  = vbuf + (size_t)NPIX * CCH;            // [8][N][128]
    float* part_l  = part_o + (size_t)KSPLIT * NPIX * CCH; // [8][N][4]
    float* cpart   = part_l + (size_t)KSPLIT * NPIX * NH;  // [144][2048]
    float* denpart = cpart + (size_t)144 * 2048;           // [144][16]
    short* qbf     = (short*)(denpart + 144 * 16);         // [N][128] bf16
    short* kbf     = qbf + (size_t)NPIX * CCH;             // [N][128] bf16
    short* vbfT    = kbf + (size_t)NPIX * CCH;             // [128][N] bf16
    short* cbf     = vbfT + (size_t)NPIX * CCH;            // [16][128] bf16

    proj_kernel<<<dim3(144, 3), 256, 0, stream>>>(
        q_img, k_img, v_img, labels, wq, bq, wk, bk, wv, bv,
        qbf, kbf, vbuf, vbfT, cpart, denpart);
    centersB_kernel<<<8, 256, 0, stream>>>(cpart, denpart, cbf);
    attn_part_kernel<<<dim3(144, KSPLIT), 256, 0, stream>>>(
        qbf, kbf, vbfT, cbf, labels, pc, part_o, part_l);
    mlp_chain_kernel<<<576, 256, 0, stream>>>(
        part_o, part_l, vbuf, w1a, b1a, w1b, b1b, w2a, b2a, w2b, b2b,
        (float*)d_out);
}

// Round 9
// 185.761 us; speedup vs baseline: 1.0141x; 1.0141x over previous
//
#include <hip/hip_runtime.h>
#include <hip/hip_bf16.h>
#include <math.h>

#define NPIX 2304
#define CCH  128
#define NH   4
#define HC   32
#define NCL  16
#define KSPLIT 8
#define KEYS 288
#define NSTEP 9
#define QSCALE 0.25503489f               // log2(e)/sqrt(32)
#define PPT  16

typedef __attribute__((ext_vector_type(8))) short short8;
typedef __attribute__((ext_vector_type(4))) float f32x4;

#if __has_builtin(__builtin_amdgcn_exp2f)
#define EXP2(x) __builtin_amdgcn_exp2f(x)
#else
#define EXP2(x) __expf((x) * 0.6931471805599453f)
#endif

static __device__ __forceinline__ short f2bf(float x) {
    __hip_bfloat16 b = __float2bfloat16(x);
    return *reinterpret_cast<short*>(&b);
}

// ---------------- Kernel 0: pack weights [IN][OUT] -> [IN/4][OUT] float4 -------
// wP[g][o] = {w[4g+0][o], w[4g+1][o], w[4g+2][o], w[4g+3][o]}
// Consumers then load 4 k-weights per (coalesced) float4 instead of 4 scalar
// dword loads 1KB apart -> 4x fewer load instructions on the critical chain.
__global__ void __launch_bounds__(256) pack_w_kernel(
        const float* __restrict__ w1a, const float* __restrict__ w1b,
        const float* __restrict__ w2a, const float* __restrict__ w2b,
        const float* __restrict__ wq,  const float* __restrict__ wk,
        const float* __restrict__ wv,
        float4* __restrict__ p1a, float4* __restrict__ p1b,
        float4* __restrict__ p2a, float4* __restrict__ p2b,
        float4* __restrict__ pq,  float4* __restrict__ pk,
        float4* __restrict__ pv) {
    const int idx = blockIdx.x * 256 + threadIdx.x;   // 0..45055
    const float* src; float4* dst; int sh, local;
    if (idx < 8192)       { src = w1a; dst = p1a; sh = 8; local = idx; }
    else if (idx < 16384) { src = w1b; dst = p1b; sh = 7; local = idx - 8192; }
    else if (idx < 24576) { src = w2a; dst = p2a; sh = 8; local = idx - 16384; }
    else if (idx < 32768) { src = w2b; dst = p2b; sh = 7; local = idx - 24576; }
    else if (idx < 36864) { src = wq;  dst = pq;  sh = 7; local = idx - 32768; }
    else if (idx < 40960) { src = wk;  dst = pk;  sh = 7; local = idx - 36864; }
    else                  { src = wv;  dst = pv;  sh = 7; local = idx - 40960; }
    const int OUT = 1 << sh;
    const int g = local >> sh, o = local & (OUT - 1);
    float4 v;
    v.x = src[(4 * g + 0) * OUT + o];
    v.y = src[(4 * g + 1) * OUT + o];
    v.z = src[(4 * g + 2) * OUT + o];
    v.w = src[(4 * g + 3) * OUT + o];
    dst[local] = v;
}

// ---------------- Kernel 1: q/k/v projections + centersA partials --------------
// r7-verified body; weight loads now packed float4 (4 k-values per load).
__global__ void __launch_bounds__(256) proj_kernel(
        const float* __restrict__ xq, const float* __restrict__ xk,
        const float* __restrict__ xv, const int* __restrict__ labels,
        const float4* __restrict__ pq, const float* __restrict__ bq,
        const float4* __restrict__ pk, const float* __restrict__ bk,
        const float4* __restrict__ pv, const float* __restrict__ bv,
        short* __restrict__ qbf, short* __restrict__ kbf,
        float* __restrict__ vbuf, short* __restrict__ vbfT,
        float* __restrict__ cpart, float* __restrict__ denpart) {
    __shared__ float xsP[CCH * PPT];          // 8 KB
    __shared__ float ls2[2 * NCL * CCH];      // 16 KB
    __shared__ float smls[32];
    const int which = blockIdx.y;
    const int pxblk = blockIdx.x;
    const int n0    = pxblk * PPT;
    const int t  = threadIdx.x;
    const int c  = t & 127;
    const int ph = t >> 7;
    const float*  x  = (which == 0) ? xq : (which == 1) ? xk : xv;
    const float4* wp = (which == 0) ? pq : (which == 1) ? pk : pv;
    const float*  b  = (which == 0) ? bq : (which == 1) ? bk : bv;

#pragma unroll
    for (int it = 0; it < 8; ++it) {
        const int flat = it * 256 + t;
        const int cc = flat >> 4;
        const int p  = flat & 15;
        xsP[flat] = x[cc * NPIX + n0 + p];
    }
    if (which == 1)
        for (int u = t; u < 2 * NCL * CCH; u += 256) ls2[u] = 0.f;
    __syncthreads();

    float acc[8];
    const float bb = b[c];
#pragma unroll
    for (int p = 0; p < 8; ++p) acc[p] = bb;

    for (int g = 0; g < CCH / 4; ++g) {
        const float4 w4 = wp[g * 128 + c];
#pragma unroll
        for (int j = 0; j < 4; ++j) {
            const float wv_ = (j == 0) ? w4.x : (j == 1) ? w4.y : (j == 2) ? w4.z : w4.w;
            const float4 xa = *(const float4*)(xsP + (4 * g + j) * PPT + ph * 8);
            const float4 xb = *(const float4*)(xsP + (4 * g + j) * PPT + ph * 8 + 4);
            acc[0] = fmaf(xa.x, wv_, acc[0]); acc[1] = fmaf(xa.y, wv_, acc[1]);
            acc[2] = fmaf(xa.z, wv_, acc[2]); acc[3] = fmaf(xa.w, wv_, acc[3]);
            acc[4] = fmaf(xb.x, wv_, acc[4]); acc[5] = fmaf(xb.y, wv_, acc[5]);
            acc[6] = fmaf(xb.z, wv_, acc[6]); acc[7] = fmaf(xb.w, wv_, acc[7]);
        }
    }

    const int nb = n0 + ph * 8;
    if (which == 0) {
#pragma unroll
        for (int p = 0; p < 8; ++p)
            qbf[(size_t)(nb + p) * CCH + c] = f2bf(acc[p] * QSCALE);
    } else if (which == 1) {
#pragma unroll
        for (int p = 0; p < 8; ++p)
            kbf[(size_t)(nb + p) * CCH + c] = f2bf(acc[p]);
        // center partials: thread owns column (ph,c) of ls2 -> race-free
        int lab8[8];
#pragma unroll
        for (int p = 0; p < 8; ++p) lab8[p] = labels[nb + p];
#pragma unroll
        for (int p = 0; p < 8; ++p)
            ls2[(ph * NCL + lab8[p]) * CCH + c] += acc[p];
        if (t < 32) {
            const int g2 = t >> 4, cl = t & 15;
            int cnt = 0;
#pragma unroll
            for (int p = 0; p < 8; ++p)
                cnt += (labels[n0 + g2 * 8 + p] == cl) ? 1 : 0;
            smls[t] = (float)cnt;
        }
        __syncthreads();
        for (int u = t; u < NCL * CCH; u += 256)
            cpart[(size_t)pxblk * 2048 + u] = ls2[u] + ls2[2048 + u];
        if (t < 16)
            denpart[pxblk * 16 + t] = smls[t] + smls[16 + t];
    } else {
#pragma unroll
        for (int p = 0; p < 8; ++p) vbuf[(size_t)(nb + p) * CCH + c] = acc[p];
        short8 s0;
#pragma unroll
        for (int p = 0; p < 8; ++p) s0[p] = f2bf(acc[p]);
        *(short8*)(vbfT + (size_t)c * NPIX + nb) = s0;
    }
}

// ---------------- Kernel 2: reduce partials -> bf16 centers ----------------
__global__ void centersB_kernel(const float* __restrict__ cpart,
                                const float* __restrict__ denpart,
                                short* __restrict__ cbf) {
    const int idx = blockIdx.x * 256 + threadIdx.x;   // 0..2047
    const int kk  = idx >> 7;
    float den = 0.f, s = 0.f;
    for (int b = 0; b < 144; ++b) den += denpart[b * 16 + kk];
    for (int b = 0; b < 144; ++b) s   += cpart[(size_t)b * 2048 + idx];
    cbf[idx] = f2bf(s / (den + 1e-6f));
}

// ---------------- Kernel 3: MFMA attention (r7-verified barrier-free body) -----
__global__ void __launch_bounds__(256, 4) attn_part_kernel(
        const short* __restrict__ qbf,  const short* __restrict__ kbf,
        const short* __restrict__ vbfT, const short* __restrict__ cbf,
        const int* __restrict__ labels, const float* __restrict__ pc,
        float* __restrict__ part_o, float* __restrict__ part_l) {
    __shared__ __align__(16) short Pl[NH][16 * 40];
    __shared__ __align__(16) float aclT[NH][16][16];
    __shared__ int   labl[KEYS];
    const int qt   = blockIdx.x;
    const int ks   = blockIdx.y;
    const int tid  = threadIdx.x;
    const int w    = tid >> 6;
    const int lane = tid & 63;
    const int quad = lane >> 4;
    const int lq   = lane & 15;
    const int i0   = qt * 16;
    const int j0   = ks * KEYS;

    for (int u = tid; u < KEYS / 4; u += 256)
        *(int4*)(labl + u * 4) = *(const int4*)(labels + j0 + u * 4);

    const short8 aq = *(const short8*)(qbf + (size_t)(i0 + lq) * CCH + w * HC + quad * 8);
    {
        const short8 bc = *(const short8*)(cbf + (size_t)lq * CCH + w * HC + quad * 8);
        f32x4 z = {0.f, 0.f, 0.f, 0.f};
        f32x4 acd = __builtin_amdgcn_mfma_f32_16x16x32_bf16(aq, bc, z, 0, 0, 0);
        *(f32x4*)(&aclT[w][lq][quad * 4]) = acd;   // [center][q-row], wave-private
    }
    int labi[4];
#pragma unroll
    for (int r = 0; r < 4; ++r) labi[r] = labels[i0 + quad * 4 + r];

    __syncthreads();   // labl ready

    const short* kp  = kbf  + (size_t)(j0 + lq) * CCH + w * HC + quad * 8;
    const short* vp  = vbfT + (size_t)(w * HC + lq) * NPIX + j0 + quad * 8;
    const float* pcp = pc   + (size_t)(i0 + quad * 4) * NPIX + j0 + lq;

    short8 k0A, k1A, v0A, v1A, k0B, k1B, v0B, v1B;
    float pcA[8], pcB[8];
    f32x4 accO0 = {0.f, 0.f, 0.f, 0.f};
    f32x4 accO1 = {0.f, 0.f, 0.f, 0.f};
    float lp[4] = {0.f, 0.f, 0.f, 0.f};

#define ISSUE(K0_, K1_, V0_, V1_, s) do {                                         \
        K0_ = *(const short8*)(kp + (size_t)(s) * 32 * CCH);                      \
        K1_ = *(const short8*)(kp + (size_t)((s) * 32 + 16) * CCH);               \
        V0_ = *(const short8*)(vp + (s) * 32);                                    \
        V1_ = *(const short8*)(vp + (size_t)16 * NPIX + (s) * 32);                \
    } while (0)

#define ISSUE_PC(dst, s) do {                                                     \
        _Pragma("unroll")                                                         \
        for (int r_ = 0; r_ < 4; ++r_) {                                          \
            dst[r_ * 2 + 0] = pcp[(size_t)r_ * NPIX + (s) * 32];                  \
            dst[r_ * 2 + 1] = pcp[(size_t)r_ * NPIX + (s) * 32 + 16];             \
        }                                                                         \
    } while (0)

#define COMPUTE(s, K0_, K1_, V0_, V1_, PCUSE) do {                                \
        _Pragma("unroll")                                                         \
        for (int kh = 0; kh < 2; ++kh) {                                          \
            const short8 bk = (kh == 0) ? K0_ : K1_;                              \
            f32x4 z = {0.f, 0.f, 0.f, 0.f};                                       \
            const f32x4 sv = __builtin_amdgcn_mfma_f32_16x16x32_bf16(aq, bk, z, 0, 0, 0);\
            const int slab = labl[(s) * 32 + kh * 16 + lq];                       \
            const f32x4 av4 = *(const f32x4*)(&aclT[w][slab][quad * 4]);          \
            _Pragma("unroll")                                                     \
            for (int r = 0; r < 4; ++r) {                                         \
                const float sc_ = (slab == labi[r]) ? sv[r] : av4[r] * PCUSE[r * 2 + kh];\
                const float p   = EXP2(sc_);                                      \
                lp[r] += p;                                                       \
                Pl[w][(quad * 4 + r) * 40 + kh * 16 + lq] = f2bf(p);              \
            }                                                                     \
        }                                                                         \
        const short8 ap = *(const short8*)(&Pl[w][lq * 40 + quad * 8]);           \
        accO0 = __builtin_amdgcn_mfma_f32_16x16x32_bf16(ap, V0_, accO0, 0, 0, 0); \
        accO1 = __builtin_amdgcn_mfma_f32_16x16x32_bf16(ap, V1_, accO1, 0, 0, 0); \
    } while (0)

    ISSUE(k0A, k1A, v0A, v1A, 0);
    ISSUE_PC(pcA, 0);
    for (int sb = 0; sb < NSTEP; sb += 2) {
        if (sb + 1 < NSTEP) { ISSUE(k0B, k1B, v0B, v1B, sb + 1); ISSUE_PC(pcB, sb + 1); }
        COMPUTE(sb, k0A, k1A, v0A, v1A, pcA);
        if (sb + 1 < NSTEP) {
            if (sb + 2 < NSTEP) { ISSUE(k0A, k1A, v0A, v1A, sb + 2); ISSUE_PC(pcA, sb + 2); }
            COMPUTE(sb + 1, k0B, k1B, v0B, v1B, pcB);
        }
    }
#undef ISSUE
#undef ISSUE_PC
#undef COMPUTE

#pragma unroll
    for (int r = 0; r < 4; ++r) {
        float v = lp[r];
        v += __shfl_xor(v, 1, 64);
        v += __shfl_xor(v, 2, 64);
        v += __shfl_xor(v, 4, 64);
        v += __shfl_xor(v, 8, 64);
        lp[r] = v;
    }
    if (lq == 0) {
#pragma unroll
        for (int r = 0; r < 4; ++r)
            part_l[((size_t)ks * NPIX + i0 + quad * 4 + r) * NH + w] = lp[r];
    }
#pragma unroll
    for (int r = 0; r < 4; ++r) {
        float* po = part_o + ((size_t)ks * NPIX + i0 + quad * 4 + r) * CCH + w * HC;
        po[lq]      = accO0[r];
        po[16 + lq] = accO1[r];
    }
}

// ---------------- Kernel 4: fused per-pixel MLP chain, 8 px/block --------------
// r7-verified 8px structure (288 blocks - the faster config per R8 A/B);
// weight loads now packed float4: 192 vs 768 load instrs per thread.
__global__ void __launch_bounds__(256) mlp_chain_kernel(
        const float* __restrict__ part_o, const float* __restrict__ part_l,
        const float* __restrict__ vbuf,
        const float4* __restrict__ p1a, const float* __restrict__ b1a,
        const float4* __restrict__ p1b, const float* __restrict__ b1b,
        const float4* __restrict__ p2a, const float* __restrict__ b2a,
        const float4* __restrict__ p2b, const float* __restrict__ b2b,
        float* __restrict__ outp) {
    __shared__ float xs[8 * CCH];             // 4 KB  attn out
    __shared__ float hL[8 * 2 * CCH];         // 8 KB  hidden (both MLPs)
    __shared__ float r1L[8 * CCH];            // 4 KB  rs1
    __shared__ float fT[CCH * 8];             // 4 KB  final transposed
    const int n0 = blockIdx.x * 8;
    const int t  = threadIdx.x;

    // stage: softmax-normalized attention output (reduce over ks splits)
    {
        const int p = t >> 5, c4 = (t & 31) * 4;
        const int hh2 = c4 >> 5;
        float ls_ = 0.f;
#pragma unroll
        for (int ks = 0; ks < KSPLIT; ++ks)
            ls_ += part_l[((size_t)ks * NPIX + n0 + p) * NH + hh2];
        float sx = 0.f, sy = 0.f, sz = 0.f, sw2 = 0.f;
#pragma unroll
        for (int ks = 0; ks < KSPLIT; ++ks) {
            const float4 v = *(const float4*)(part_o + ((size_t)ks * NPIX + n0 + p) * CCH + c4);
            sx += v.x; sy += v.y; sz += v.z; sw2 += v.w;
        }
        const float inv = 1.f / ls_;
        xs[p * CCH + c4 + 0] = sx * inv;
        xs[p * CCH + c4 + 1] = sy * inv;
        xs[p * CCH + c4 + 2] = sz * inv;
        xs[p * CCH + c4 + 3] = sw2 * inv;
    }
    __syncthreads();

    const int c  = t & 127;
    const int pg = t >> 7;                    // wave-uniform: px pg*4..pg*4+3

    // ---- MLP1 hidden: thread owns hidden unit t for 8 px ----
    {
        float ha[8];
        const float b1 = b1a[t];
#pragma unroll
        for (int p = 0; p < 8; ++p) ha[p] = b1;
        for (int g = 0; g < CCH / 4; ++g) {
            const float4 w4 = p1a[g * 2 * CCH + t];
#pragma unroll
            for (int p = 0; p < 8; ++p) {
                const float4 xv = *(const float4*)(xs + p * CCH + g * 4);
                ha[p] = fmaf(xv.x, w4.x, ha[p]); ha[p] = fmaf(xv.y, w4.y, ha[p]);
                ha[p] = fmaf(xv.z, w4.z, ha[p]); ha[p] = fmaf(xv.w, w4.w, ha[p]);
            }
        }
#pragma unroll
        for (int p = 0; p < 8; ++p) {
            const float v = ha[p];
            hL[p * 2 * CCH + t] = (v > 0.f) ? v : 0.01f * v;
        }
    }
    __syncthreads();

    // ---- MLP1 out + residual v -> rs1 (LDS); thread owns channel c for 4 px ----
    {
        float oa[4];
        const float bo = b1b[c];
#pragma unroll
        for (int j = 0; j < 4; ++j) oa[j] = bo;
        for (int g = 0; g < 2 * CCH / 4; ++g) {
            const float4 w4 = p1b[g * CCH + c];
#pragma unroll
            for (int j = 0; j < 4; ++j) {
                const float4 hv = *(const float4*)(hL + (pg * 4 + j) * 2 * CCH + g * 4);
                oa[j] = fmaf(hv.x, w4.x, oa[j]); oa[j] = fmaf(hv.y, w4.y, oa[j]);
                oa[j] = fmaf(hv.z, w4.z, oa[j]); oa[j] = fmaf(hv.w, w4.w, oa[j]);
            }
        }
#pragma unroll
        for (int j = 0; j < 4; ++j)
            r1L[(pg * 4 + j) * CCH + c] =
                vbuf[(size_t)(n0 + pg * 4 + j) * CCH + c] + oa[j];
    }
    __syncthreads();

    // ---- MLP2 hidden (reads rs1, overwrites hL) ----
    {
        float ha[8];
        const float b2 = b2a[t];
#pragma unroll
        for (int p = 0; p < 8; ++p) ha[p] = b2;
        for (int g = 0; g < CCH / 4; ++g) {
            const float4 w4 = p2a[g * 2 * CCH + t];
#pragma unroll
            for (int p = 0; p < 8; ++p) {
                const float4 xv = *(const float4*)(r1L + p * CCH + g * 4);
                ha[p] = fmaf(xv.x, w4.x, ha[p]); ha[p] = fmaf(xv.y, w4.y, ha[p]);
                ha[p] = fmaf(xv.z, w4.z, ha[p]); ha[p] = fmaf(xv.w, w4.w, ha[p]);
            }
        }
        __syncthreads();   // hL WAR
#pragma unroll
        for (int p = 0; p < 8; ++p) {
            const float v = ha[p];
            hL[p * 2 * CCH + t] = (v > 0.f) ? v : 0.01f * v;
        }
    }
    __syncthreads();

    // ---- MLP2 out + residual rs1 -> fT[c][px] ----
    {
        float oa[4];
        const float bo = b2b[c];
#pragma unroll
        for (int j = 0; j < 4; ++j) oa[j] = bo;
        for (int g = 0; g < 2 * CCH / 4; ++g) {
            const float4 w4 = p2b[g * CCH + c];
#pragma unroll
            for (int j = 0; j < 4; ++j) {
                const float4 hv = *(const float4*)(hL + (pg * 4 + j) * 2 * CCH + g * 4);
                oa[j] = fmaf(hv.x, w4.x, oa[j]); oa[j] = fmaf(hv.y, w4.y, oa[j]);
                oa[j] = fmaf(hv.z, w4.z, oa[j]); oa[j] = fmaf(hv.w, w4.w, oa[j]);
            }
        }
#pragma unroll
        for (int j = 0; j < 4; ++j)
            fT[c * 8 + pg * 4 + j] = r1L[(pg * 4 + j) * CCH + c] + oa[j];
    }
    __syncthreads();

    // ---- coalesced final store: out[c][n0..n0+8) as 2 x float4 per row ----
    {
        const int cc = t >> 1, half = t & 1;
        const float4 v = *(const float4*)(fT + cc * 8 + half * 4);
        *(float4*)(outp + (size_t)cc * NPIX + n0 + half * 4) = v;
    }
}

extern "C" void kernel_launch(void* const* d_in, const int* in_sizes, int n_in,
                              void* d_out, int out_size, void* d_ws, size_t ws_size,
                              hipStream_t stream) {
    const float* q_img = (const float*)d_in[0];
    const float* k_img = (const float*)d_in[1];
    const float* v_img = (const float*)d_in[2];
    const float* pc    = (const float*)d_in[3];
    const int*   labels= (const int*)  d_in[4];
    const float* wq = (const float*)d_in[5];   const float* bq = (const float*)d_in[6];
    const float* wk = (const float*)d_in[7];   const float* bk = (const float*)d_in[8];
    const float* wv = (const float*)d_in[9];   const float* bv = (const float*)d_in[10];
    const float* w1a = (const float*)d_in[11]; const float* b1a = (const float*)d_in[12];
    const float* w1b = (const float*)d_in[13]; const float* b1b = (const float*)d_in[14];
    const float* w2a = (const float*)d_in[15]; const float* b2a = (const float*)d_in[16];
    const float* w2b = (const float*)d_in[17]; const float* b2b = (const float*)d_in[18];

    float* fw = (float*)d_ws;
    float* vbuf    = fw;                                   // [N][128]
    float* part_o  = vbuf + (size_t)NPIX * CCH;            // [8][N][128]
    float* part_l  = part_o + (size_t)KSPLIT * NPIX * CCH; // [8][N][4]
    float* cpart   = part_l + (size_t)KSPLIT * NPIX * NH;  // [144][2048]
    float* denpart = cpart + (size_t)144 * 2048;           // [144][16]
    float* pkd     = denpart + 144 * 16;                   // packed weights (16B-aligned)
    float4* p1a = (float4*)pkd;                            // [32][256]
    float4* p1b = p1a + 8192;                              // [64][128]
    float4* p2a = p1b + 8192;                              // [32][256]
    float4* p2b = p2a + 8192;                              // [64][128]
    float4* pq  = p2b + 8192;                              // [32][128]
    float4* pk4 = pq + 4096;                               // [32][128]
    float4* pv4 = pk4 + 4096;                              // [32][128]
    short* qbf     = (short*)(pv4 + 4096);                 // [N][128] bf16
    short* kbf     = qbf + (size_t)NPIX * CCH;             // [N][128] bf16
    short* vbfT    = kbf + (size_t)NPIX * CCH;             // [128][N] bf16
    short* cbf     = vbfT + (size_t)NPIX * CCH;            // [16][128] bf16

    pack_w_kernel<<<176, 256, 0, stream>>>(
        w1a, w1b, w2a, w2b, wq, wk, wv, p1a, p1b, p2a, p2b, pq, pk4, pv4);
    proj_kernel<<<dim3(144, 3), 256, 0, stream>>>(
        q_img, k_img, v_img, labels, pq, bq, pk4, bk, pv4, bv,
        qbf, kbf, vbuf, vbfT, cpart, denpart);
    centersB_kernel<<<8, 256, 0, stream>>>(cpart, denpart, cbf);
    attn_part_kernel<<<dim3(144, KSPLIT), 256, 0, stream>>>(
        qbf, kbf, vbfT, cbf, labels, pc, part_o, part_l);
    mlp_chain_kernel<<<288, 256, 0, stream>>>(
        part_o, part_l, vbuf, p1a, b1a, p1b, b1b, p2a, b2a, p2b, b2b,
        (float*)d_out);
}

// Round 10
// 157.533 us; speedup vs baseline: 1.1959x; 1.1792x over previous
//
#include <hip/hip_runtime.h>
#include <hip/hip_bf16.h>
#include <math.h>

#define NPIX 2304
#define CCH  128
#define NH   4
#define HC   32
#define NCL  16
#define KSPLIT 8
#define KEYS 288
#define NSTEP 9
#define QSCALE 0.25503489f               // log2(e)/sqrt(32)
#define PPT  16

typedef __attribute__((ext_vector_type(8))) short short8;
typedef __attribute__((ext_vector_type(4))) short short4v;
typedef __attribute__((ext_vector_type(4))) float f32x4;

#if __has_builtin(__builtin_amdgcn_exp2f)
#define EXP2(x) __builtin_amdgcn_exp2f(x)
#else
#define EXP2(x) __expf((x) * 0.6931471805599453f)
#endif

static __device__ __forceinline__ short f2bf(float x) {
    __hip_bfloat16 b = __float2bfloat16(x);
    return *reinterpret_cast<short*>(&b);
}

// ---------------- Kernel 0: weight prep ----------------------------------------
// proj weights: [IN][OUT] f32 -> [IN/4][OUT] float4 (r9-verified transform)
// mlp  weights: [IN][OUT] f32 -> [OUT][IN] bf16 (B-operand rows for MFMA)
__global__ void __launch_bounds__(256) pack_w_kernel(
        const float* __restrict__ wq,  const float* __restrict__ wk,
        const float* __restrict__ wv,
        const float* __restrict__ w1a, const float* __restrict__ w1b,
        const float* __restrict__ w2a, const float* __restrict__ w2b,
        float4* __restrict__ pq,  float4* __restrict__ pk,
        float4* __restrict__ pv,
        short* __restrict__ t1a, short* __restrict__ t1b,
        short* __restrict__ t2a, short* __restrict__ t2b) {
    const int idx = blockIdx.x * 256 + threadIdx.x;   // 0..28671
    if (idx < 12288) {                                 // proj f32 packs
        const int which = idx >> 12, local = idx & 4095;
        const float* src = (which == 0) ? wq : (which == 1) ? wk : wv;
        float4*      dst = (which == 0) ? pq : (which == 1) ? pk : pv;
        const int g = local >> 7, o = local & 127;
        float4 v;
        v.x = src[(4 * g + 0) * 128 + o];
        v.y = src[(4 * g + 1) * 128 + o];
        v.z = src[(4 * g + 2) * 128 + o];
        v.w = src[(4 * g + 3) * 128 + o];
        dst[local] = v;
    } else {                                           // mlp bf16 transposes
        const int i2 = idx - 12288;
        const int which = i2 >> 12, local = i2 & 4095;
        short8 s;
        if (which == 0 || which == 2) {                // [128][256] -> [256][128]
            const float* src = (which == 0) ? w1a : w2a;
            short*       dst = (which == 0) ? t1a : t2a;
            const int o = local >> 4, g = local & 15;  // o: 256 outs, g: 16 k-groups
#pragma unroll
            for (int j = 0; j < 8; ++j) s[j] = f2bf(src[(g * 8 + j) * 256 + o]);
            *(short8*)(dst + (size_t)o * 128 + g * 8) = s;
        } else {                                       // [256][128] -> [128][256]
            const float* src = (which == 1) ? w1b : w2b;
            short*       dst = (which == 1) ? t1b : t2b;
            const int o = local >> 5, g = local & 31;  // o: 128 outs, g: 32 k-groups
#pragma unroll
            for (int j = 0; j < 8; ++j) s[j] = f2bf(src[(g * 8 + j) * 128 + o]);
            *(short8*)(dst + (size_t)o * 256 + g * 8) = s;
        }
    }
}

// ---------------- Kernel 1: q/k/v projections + centersA partials (r9 body) ----
__global__ void __launch_bounds__(256) proj_kernel(
        const float* __restrict__ xq, const float* __restrict__ xk,
        const float* __restrict__ xv, const int* __restrict__ labels,
        const float4* __restrict__ pq, const float* __restrict__ bq,
        const float4* __restrict__ pk, const float* __restrict__ bk,
        const float4* __restrict__ pv, const float* __restrict__ bv,
        short* __restrict__ qbf, short* __restrict__ kbf,
        float* __restrict__ vbuf, short* __restrict__ vbfT,
        float* __restrict__ cpart, float* __restrict__ denpart) {
    __shared__ float xsP[CCH * PPT];          // 8 KB
    __shared__ float ls2[2 * NCL * CCH];      // 16 KB
    __shared__ float smls[32];
    const int which = blockIdx.y;
    const int pxblk = blockIdx.x;
    const int n0    = pxblk * PPT;
    const int t  = threadIdx.x;
    const int c  = t & 127;
    const int ph = t >> 7;
    const float*  x  = (which == 0) ? xq : (which == 1) ? xk : xv;
    const float4* wp = (which == 0) ? pq : (which == 1) ? pk : pv;
    const float*  b  = (which == 0) ? bq : (which == 1) ? bk : bv;

#pragma unroll
    for (int it = 0; it < 8; ++it) {
        const int flat = it * 256 + t;
        const int cc = flat >> 4;
        const int p  = flat & 15;
        xsP[flat] = x[cc * NPIX + n0 + p];
    }
    if (which == 1)
        for (int u = t; u < 2 * NCL * CCH; u += 256) ls2[u] = 0.f;
    __syncthreads();

    float acc[8];
    const float bb = b[c];
#pragma unroll
    for (int p = 0; p < 8; ++p) acc[p] = bb;

    for (int g = 0; g < CCH / 4; ++g) {
        const float4 w4 = wp[g * 128 + c];
#pragma unroll
        for (int j = 0; j < 4; ++j) {
            const float wv_ = (j == 0) ? w4.x : (j == 1) ? w4.y : (j == 2) ? w4.z : w4.w;
            const float4 xa = *(const float4*)(xsP + (4 * g + j) * PPT + ph * 8);
            const float4 xb = *(const float4*)(xsP + (4 * g + j) * PPT + ph * 8 + 4);
            acc[0] = fmaf(xa.x, wv_, acc[0]); acc[1] = fmaf(xa.y, wv_, acc[1]);
            acc[2] = fmaf(xa.z, wv_, acc[2]); acc[3] = fmaf(xa.w, wv_, acc[3]);
            acc[4] = fmaf(xb.x, wv_, acc[4]); acc[5] = fmaf(xb.y, wv_, acc[5]);
            acc[6] = fmaf(xb.z, wv_, acc[6]); acc[7] = fmaf(xb.w, wv_, acc[7]);
        }
    }

    const int nb = n0 + ph * 8;
    if (which == 0) {
#pragma unroll
        for (int p = 0; p < 8; ++p)
            qbf[(size_t)(nb + p) * CCH + c] = f2bf(acc[p] * QSCALE);
    } else if (which == 1) {
#pragma unroll
        for (int p = 0; p < 8; ++p)
            kbf[(size_t)(nb + p) * CCH + c] = f2bf(acc[p]);
        int lab8[8];
#pragma unroll
        for (int p = 0; p < 8; ++p) lab8[p] = labels[nb + p];
#pragma unroll
        for (int p = 0; p < 8; ++p)
            ls2[(ph * NCL + lab8[p]) * CCH + c] += acc[p];
        if (t < 32) {
            const int g2 = t >> 4, cl = t & 15;
            int cnt = 0;
#pragma unroll
            for (int p = 0; p < 8; ++p)
                cnt += (labels[n0 + g2 * 8 + p] == cl) ? 1 : 0;
            smls[t] = (float)cnt;
        }
        __syncthreads();
        for (int u = t; u < NCL * CCH; u += 256)
            cpart[(size_t)pxblk * 2048 + u] = ls2[u] + ls2[2048 + u];
        if (t < 16)
            denpart[pxblk * 16 + t] = smls[t] + smls[16 + t];
    } else {
#pragma unroll
        for (int p = 0; p < 8; ++p) vbuf[(size_t)(nb + p) * CCH + c] = acc[p];
        short8 s0;
#pragma unroll
        for (int p = 0; p < 8; ++p) s0[p] = f2bf(acc[p]);
        *(short8*)(vbfT + (size_t)c * NPIX + nb) = s0;
    }
}

// ---------------- Kernel 2: reduce partials -> bf16 centers ----------------
__global__ void centersB_kernel(const float* __restrict__ cpart,
                                const float* __restrict__ denpart,
                                short* __restrict__ cbf) {
    const int idx = blockIdx.x * 256 + threadIdx.x;   // 0..2047
    const int kk  = idx >> 7;
    float den = 0.f, s = 0.f;
    for (int b = 0; b < 144; ++b) den += denpart[b * 16 + kk];
    for (int b = 0; b < 144; ++b) s   += cpart[(size_t)b * 2048 + idx];
    cbf[idx] = f2bf(s / (den + 1e-6f));
}

// ---------------- Kernel 3: MFMA attention (r9-verified barrier-free body) -----
__global__ void __launch_bounds__(256, 4) attn_part_kernel(
        const short* __restrict__ qbf,  const short* __restrict__ kbf,
        const short* __restrict__ vbfT, const short* __restrict__ cbf,
        const int* __restrict__ labels, const float* __restrict__ pc,
        float* __restrict__ part_o, float* __restrict__ part_l) {
    __shared__ __align__(16) short Pl[NH][16 * 40];
    __shared__ __align__(16) float aclT[NH][16][16];
    __shared__ int   labl[KEYS];
    const int qt   = blockIdx.x;
    const int ks   = blockIdx.y;
    const int tid  = threadIdx.x;
    const int w    = tid >> 6;
    const int lane = tid & 63;
    const int quad = lane >> 4;
    const int lq   = lane & 15;
    const int i0   = qt * 16;
    const int j0   = ks * KEYS;

    for (int u = tid; u < KEYS / 4; u += 256)
        *(int4*)(labl + u * 4) = *(const int4*)(labels + j0 + u * 4);

    const short8 aq = *(const short8*)(qbf + (size_t)(i0 + lq) * CCH + w * HC + quad * 8);
    {
        const short8 bc = *(const short8*)(cbf + (size_t)lq * CCH + w * HC + quad * 8);
        f32x4 z = {0.f, 0.f, 0.f, 0.f};
        f32x4 acd = __builtin_amdgcn_mfma_f32_16x16x32_bf16(aq, bc, z, 0, 0, 0);
        *(f32x4*)(&aclT[w][lq][quad * 4]) = acd;   // [center][q-row], wave-private
    }
    int labi[4];
#pragma unroll
    for (int r = 0; r < 4; ++r) labi[r] = labels[i0 + quad * 4 + r];

    __syncthreads();   // labl ready

    const short* kp  = kbf  + (size_t)(j0 + lq) * CCH + w * HC + quad * 8;
    const short* vp  = vbfT + (size_t)(w * HC + lq) * NPIX + j0 + quad * 8;
    const float* pcp = pc   + (size_t)(i0 + quad * 4) * NPIX + j0 + lq;

    short8 k0A, k1A, v0A, v1A, k0B, k1B, v0B, v1B;
    float pcA[8], pcB[8];
    f32x4 accO0 = {0.f, 0.f, 0.f, 0.f};
    f32x4 accO1 = {0.f, 0.f, 0.f, 0.f};
    float lp[4] = {0.f, 0.f, 0.f, 0.f};

#define ISSUE(K0_, K1_, V0_, V1_, s) do {                                         \
        K0_ = *(const short8*)(kp + (size_t)(s) * 32 * CCH);                      \
        K1_ = *(const short8*)(kp + (size_t)((s) * 32 + 16) * CCH);               \
        V0_ = *(const short8*)(vp + (s) * 32);                                    \
        V1_ = *(const short8*)(vp + (size_t)16 * NPIX + (s) * 32);                \
    } while (0)

#define ISSUE_PC(dst, s) do {                                                     \
        _Pragma("unroll")                                                         \
        for (int r_ = 0; r_ < 4; ++r_) {                                          \
            dst[r_ * 2 + 0] = pcp[(size_t)r_ * NPIX + (s) * 32];                  \
            dst[r_ * 2 + 1] = pcp[(size_t)r_ * NPIX + (s) * 32 + 16];             \
        }                                                                         \
    } while (0)

#define COMPUTE(s, K0_, K1_, V0_, V1_, PCUSE) do {                                \
        _Pragma("unroll")                                                         \
        for (int kh = 0; kh < 2; ++kh) {                                          \
            const short8 bk = (kh == 0) ? K0_ : K1_;                              \
            f32x4 z = {0.f, 0.f, 0.f, 0.f};                                       \
            const f32x4 sv = __builtin_amdgcn_mfma_f32_16x16x32_bf16(aq, bk, z, 0, 0, 0);\
            const int slab = labl[(s) * 32 + kh * 16 + lq];                       \
            const f32x4 av4 = *(const f32x4*)(&aclT[w][slab][quad * 4]);          \
            _Pragma("unroll")                                                     \
            for (int r = 0; r < 4; ++r) {                                         \
                const float sc_ = (slab == labi[r]) ? sv[r] : av4[r] * PCUSE[r * 2 + kh];\
                const float p   = EXP2(sc_);                                      \
                lp[r] += p;                                                       \
                Pl[w][(quad * 4 + r) * 40 + kh * 16 + lq] = f2bf(p);              \
            }                                                                     \
        }                                                                         \
        const short8 ap = *(const short8*)(&Pl[w][lq * 40 + quad * 8]);           \
        accO0 = __builtin_amdgcn_mfma_f32_16x16x32_bf16(ap, V0_, accO0, 0, 0, 0); \
        accO1 = __builtin_amdgcn_mfma_f32_16x16x32_bf16(ap, V1_, accO1, 0, 0, 0); \
    } while (0)

    ISSUE(k0A, k1A, v0A, v1A, 0);
    ISSUE_PC(pcA, 0);
    for (int sb = 0; sb < NSTEP; sb += 2) {
        if (sb + 1 < NSTEP) { ISSUE(k0B, k1B, v0B, v1B, sb + 1); ISSUE_PC(pcB, sb + 1); }
        COMPUTE(sb, k0A, k1A, v0A, v1A, pcA);
        if (sb + 1 < NSTEP) {
            if (sb + 2 < NSTEP) { ISSUE(k0A, k1A, v0A, v1A, sb + 2); ISSUE_PC(pcA, sb + 2); }
            COMPUTE(sb + 1, k0B, k1B, v0B, v1B, pcB);
        }
    }
#undef ISSUE
#undef ISSUE_PC
#undef COMPUTE

#pragma unroll
    for (int r = 0; r < 4; ++r) {
        float v = lp[r];
        v += __shfl_xor(v, 1, 64);
        v += __shfl_xor(v, 2, 64);
        v += __shfl_xor(v, 4, 64);
        v += __shfl_xor(v, 8, 64);
        lp[r] = v;
    }
    if (lq == 0) {
#pragma unroll
        for (int r = 0; r < 4; ++r)
            part_l[((size_t)ks * NPIX + i0 + quad * 4 + r) * NH + w] = lp[r];
    }
#pragma unroll
    for (int r = 0; r < 4; ++r) {
        float* po = part_o + ((size_t)ks * NPIX + i0 + quad * 4 + r) * CCH + w * HC;
        po[lq]      = accO0[r];
        po[16 + lq] = accO1[r];
    }
}

// ---------------- Kernel 4: MFMA MLP chain, 16 px/block ------------------------
// Matmul-shaped work moved to matrix cores: 64 MFMA/wave replaces ~4096 scalar
// FMAs + ~1024 broadcast ds_reads (the R8/R9-invariant bottleneck).
// A-fragments (pixel rows) from bf16 LDS; B-fragments (weight rows) straight
// from L2-resident [out][in] bf16 weights. Residuals stay fp32; rs1 kept in
// regs for the final residual (MLP1o/MLP2o lane mappings are identical).
#define XS 136   // 128+8 shorts, 16B-aligned rows
#define HS 264   // 256+8
__global__ void __launch_bounds__(256) mlp_mfma_kernel(
        const float* __restrict__ part_o, const float* __restrict__ part_l,
        const float* __restrict__ vbuf,
        const short* __restrict__ t1a, const float* __restrict__ b1a,
        const short* __restrict__ t1b, const float* __restrict__ b1b,
        const short* __restrict__ t2a, const float* __restrict__ b2a,
        const short* __restrict__ t2b, const float* __restrict__ b2b,
        float* __restrict__ outp) {
    __shared__ __align__(16) short xbf[16 * XS];    // x (attn out) bf16
    __shared__ __align__(16) short hbf[16 * HS];    // hidden bf16 (both MLPs)
    __shared__ __align__(16) short r1bf[16 * XS];   // rs1 bf16 (MLP2 input)
    __shared__ float fT[128 * 20];                  // final transposed (+pad)
    const int n0 = blockIdx.x * 16;
    const int t  = threadIdx.x;
    const int w  = t >> 6, lane = t & 63, quad = lane >> 4, lq = lane & 15;

    // stage: softmax-normalize attn partials -> bf16 x
    for (int u = t; u < 512; u += 256) {
        const int p = u >> 5, c4 = (u & 31) * 4, hh = c4 >> 5;
        float ls_ = 0.f;
#pragma unroll
        for (int ks = 0; ks < KSPLIT; ++ks)
            ls_ += part_l[((size_t)ks * NPIX + n0 + p) * NH + hh];
        float sx = 0.f, sy = 0.f, sz = 0.f, sw2 = 0.f;
#pragma unroll
        for (int ks = 0; ks < KSPLIT; ++ks) {
            const float4 v = *(const float4*)(part_o + ((size_t)ks * NPIX + n0 + p) * CCH + c4);
            sx += v.x; sy += v.y; sz += v.z; sw2 += v.w;
        }
        const float inv = 1.f / ls_;
        short4v s;
        s[0] = f2bf(sx * inv); s[1] = f2bf(sy * inv);
        s[2] = f2bf(sz * inv); s[3] = f2bf(sw2 * inv);
        *(short4v*)(xbf + p * XS + c4) = s;
    }
    __syncthreads();

    // MLP1 hidden: wave w -> outs [w*64, w*64+64), k=128
    {
        short8 a[4];
#pragma unroll
        for (int ks = 0; ks < 4; ++ks)
            a[ks] = *(const short8*)(xbf + lq * XS + ks * 32 + quad * 8);
#pragma unroll
        for (int tile = 0; tile < 4; ++tile) {
            const int out0 = w * 64 + tile * 16;
            f32x4 acc = {0.f, 0.f, 0.f, 0.f};
#pragma unroll
            for (int ks = 0; ks < 4; ++ks) {
                const short8 b = *(const short8*)(t1a + (size_t)(out0 + lq) * 128 + ks * 32 + quad * 8);
                acc = __builtin_amdgcn_mfma_f32_16x16x32_bf16(a[ks], b, acc, 0, 0, 0);
            }
            const float bb = b1a[out0 + lq];
#pragma unroll
            for (int r = 0; r < 4; ++r) {
                float v = acc[r] + bb;
                v = (v > 0.f) ? v : 0.01f * v;
                hbf[(quad * 4 + r) * HS + out0 + lq] = f2bf(v);
            }
        }
    }
    __syncthreads();

    // MLP1 out + residual v: wave w -> outs [w*32, w*32+32), k=256
    float rs1f[2][4];
    {
        short8 a[8];
#pragma unroll
        for (int ks = 0; ks < 8; ++ks)
            a[ks] = *(const short8*)(hbf + lq * HS + ks * 32 + quad * 8);
#pragma unroll
        for (int tile = 0; tile < 2; ++tile) {
            const int out0 = w * 32 + tile * 16;
            f32x4 acc = {0.f, 0.f, 0.f, 0.f};
#pragma unroll
            for (int ks = 0; ks < 8; ++ks) {
                const short8 b = *(const short8*)(t1b + (size_t)(out0 + lq) * 256 + ks * 32 + quad * 8);
                acc = __builtin_amdgcn_mfma_f32_16x16x32_bf16(a[ks], b, acc, 0, 0, 0);
            }
            const float bb = b1b[out0 + lq];
#pragma unroll
            for (int r = 0; r < 4; ++r) {
                const float v = acc[r] + bb +
                    vbuf[(size_t)(n0 + quad * 4 + r) * CCH + out0 + lq];
                rs1f[tile][r] = v;
                r1bf[(quad * 4 + r) * XS + out0 + lq] = f2bf(v);
            }
        }
    }
    __syncthreads();

    // MLP2 hidden
    {
        short8 a[4];
#pragma unroll
        for (int ks = 0; ks < 4; ++ks)
            a[ks] = *(const short8*)(r1bf + lq * XS + ks * 32 + quad * 8);
#pragma unroll
        for (int tile = 0; tile < 4; ++tile) {
            const int out0 = w * 64 + tile * 16;
            f32x4 acc = {0.f, 0.f, 0.f, 0.f};
#pragma unroll
            for (int ks = 0; ks < 4; ++ks) {
                const short8 b = *(const short8*)(t2a + (size_t)(out0 + lq) * 128 + ks * 32 + quad * 8);
                acc = __builtin_amdgcn_mfma_f32_16x16x32_bf16(a[ks], b, acc, 0, 0, 0);
            }
            const float bb = b2a[out0 + lq];
#pragma unroll
            for (int r = 0; r < 4; ++r) {
                float v = acc[r] + bb;
                v = (v > 0.f) ? v : 0.01f * v;
                hbf[(quad * 4 + r) * HS + out0 + lq] = f2bf(v);
            }
        }
    }
    __syncthreads();

    // MLP2 out + residual rs1 (regs) -> fT[c][px]
    {
        short8 a[8];
#pragma unroll
        for (int ks = 0; ks < 8; ++ks)
            a[ks] = *(const short8*)(hbf + lq * HS + ks * 32 + quad * 8);
#pragma unroll
        for (int tile = 0; tile < 2; ++tile) {
            const int out0 = w * 32 + tile * 16;
            f32x4 acc = {0.f, 0.f, 0.f, 0.f};
#pragma unroll
            for (int ks = 0; ks < 8; ++ks) {
                const short8 b = *(const short8*)(t2b + (size_t)(out0 + lq) * 256 + ks * 32 + quad * 8);
                acc = __builtin_amdgcn_mfma_f32_16x16x32_bf16(a[ks], b, acc, 0, 0, 0);
            }
            const float bb = b2b[out0 + lq];
#pragma unroll
            for (int r = 0; r < 4; ++r)
                fT[(out0 + lq) * 20 + quad * 4 + r] = acc[r] + bb + rs1f[tile][r];
        }
    }
    __syncthreads();

    // coalesced final store: out[c][n0..n0+16) as 4 x float4 per row
    for (int u = t; u < 512; u += 256) {
        const int row = u >> 2, seg = u & 3;
        const float4 v = *(const float4*)(fT + row * 20 + seg * 4);
        *(float4*)(outp + (size_t)row * NPIX + n0 + seg * 4) = v;
    }
}

extern "C" void kernel_launch(void* const* d_in, const int* in_sizes, int n_in,
                              void* d_out, int out_size, void* d_ws, size_t ws_size,
                              hipStream_t stream) {
    const float* q_img = (const float*)d_in[0];
    const float* k_img = (const float*)d_in[1];
    const float* v_img = (const float*)d_in[2];
    const float* pc    = (const float*)d_in[3];
    const int*   labels= (const int*)  d_in[4];
    const float* wq = (const float*)d_in[5];   const float* bq = (const float*)d_in[6];
    const float* wk = (const float*)d_in[7];   const float* bk = (const float*)d_in[8];
    const float* wv = (const float*)d_in[9];   const float* bv = (const float*)d_in[10];
    const float* w1a = (const float*)d_in[11]; const float* b1a = (const float*)d_in[12];
    const float* w1b = (const float*)d_in[13]; const float* b1b = (const float*)d_in[14];
    const float* w2a = (const float*)d_in[15]; const float* b2a = (const float*)d_in[16];
    const float* w2b = (const float*)d_in[17]; const float* b2b = (const float*)d_in[18];

    float* fw = (float*)d_ws;
    float* vbuf    = fw;                                   // [N][128]
    float* part_o  = vbuf + (size_t)NPIX * CCH;            // [8][N][128]
    float* part_l  = part_o + (size_t)KSPLIT * NPIX * CCH; // [8][N][4]
    float* cpart   = part_l + (size_t)KSPLIT * NPIX * NH;  // [144][2048]
    float* denpart = cpart + (size_t)144 * 2048;           // [144][16]
    float4* pq  = (float4*)(denpart + 144 * 16);           // [32][128] f32 packs
    float4* pk4 = pq + 4096;
    float4* pv4 = pk4 + 4096;
    short* t1a  = (short*)(pv4 + 4096);                    // [256][128] bf16
    short* t1b  = t1a + 32768;                             // [128][256] bf16
    short* t2a  = t1b + 32768;                             // [256][128] bf16
    short* t2b  = t2a + 32768;                             // [128][256] bf16
    short* qbf  = t2b + 32768;                             // [N][128] bf16
    short* kbf  = qbf + (size_t)NPIX * CCH;                // [N][128] bf16
    short* vbfT = kbf + (size_t)NPIX * CCH;                // [128][N] bf16
    short* cbf  = vbfT + (size_t)NPIX * CCH;               // [16][128] bf16

    pack_w_kernel<<<112, 256, 0, stream>>>(
        wq, wk, wv, w1a, w1b, w2a, w2b, pq, pk4, pv4, t1a, t1b, t2a, t2b);
    proj_kernel<<<dim3(144, 3), 256, 0, stream>>>(
        q_img, k_img, v_img, labels, pq, bq, pk4, bk, pv4, bv,
        qbf, kbf, vbuf, vbfT, cpart, denpart);
    centersB_kernel<<<8, 256, 0, stream>>>(cpart, denpart, cbf);
    attn_part_kernel<<<dim3(144, KSPLIT), 256, 0, stream>>>(
        qbf, kbf, vbfT, cbf, labels, pc, part_o, part_l);
    mlp_mfma_kernel<<<144, 256, 0, stream>>>(
        part_o, part_l, vbuf, t1a, b1a, t1b, b1b, t2a, b2a, t2b, b2b,
        (float*)d_out);
}